// Round 2
// 1216.877 us; speedup vs baseline: 1.1685x; 1.1685x over previous
//
#include <hip/hip_runtime.h>
#include <hip/hip_bf16.h>
#include <math.h>

#define HW2 196
#define CIN 1024

using f32x4 = __attribute__((ext_vector_type(4))) float;
using s16x8 = __attribute__((ext_vector_type(8))) short;

__device__ __forceinline__ float tanh_fast(float x) {
  float cx = fminf(fmaxf(x, -15.f), 15.f);
  float e = __expf(2.f * cx);
  return (e - 1.f) / (e + 1.f);
}

// pack 2 floats -> 2 bf16 (RNE, identical rounding to the old bit-trick);
// compiler emits v_cvt_pk_bf16_f32.
__device__ __forceinline__ unsigned int pkbf(float a, float b) {
  union { __hip_bfloat162 h; unsigned int u; } v;
  v.h = __float22bfloat162_rn(make_float2(a, b));
  return v.u;
}

// ---------------- precompute: attr tables + BN fold -------------------------
__global__ void k_pre1(const float* __restrict__ attr_emb,
                       const float* __restrict__ Wt1, const float* __restrict__ bt1,
                       const float* __restrict__ Wt2, const float* __restrict__ bt2,
                       const float* __restrict__ bc, const float* __restrict__ gamma,
                       const float* __restrict__ beta, const float* __restrict__ mean,
                       const float* __restrict__ var,
                       float* __restrict__ attr1_tab, float* __restrict__ attr2_tab,
                       float* __restrict__ bnA, float* __restrict__ bnB) {
  int gid = blockIdx.x * 256 + threadIdx.x;
  if (gid < 4096) {
    int a = gid >> 9, j = gid & 511;
    const float* e = attr_emb + a * 512;
    const float* w1 = Wt1 + j * 512;
    const float* w2 = Wt2 + j * 512;
    float d1 = 0.f, d2 = 0.f;
    for (int i = 0; i < 512; ++i) {
      float ev = e[i];
      d1 += ev * w1[i];
      d2 += ev * w2[i];
    }
    attr1_tab[gid] = tanh_fast(d1 + bt1[j]);
    float r = d2 + bt2[j];
    attr2_tab[gid] = r > 0.f ? r : 0.f;
  } else if (gid < 4608) {
    int o = gid - 4096;
    float A = gamma[o] * rsqrtf(var[o] + 1e-5f);
    bnA[o] = A;
    bnB[o] = (bc[o] - mean[o]) * A + beta[o];
  }
}

// t2[a][j] = W1[j, 1024:1536] . attr2[a] + b1[j]   (blocks 0..15)
// wcbf = bf16(Wc)                                  (blocks 16..143)
__global__ void k_pre2(const float* __restrict__ W1, const float* __restrict__ b1,
                       const float* __restrict__ attr2_tab, float* __restrict__ t2,
                       const float* __restrict__ Wc, unsigned short* __restrict__ wcbf) {
  int bid = blockIdx.x;
  if (bid < 16) {
    int gid = bid * 256 + threadIdx.x;  // < 4096
    int a = gid >> 9, j = gid & 511;
    const float* w = W1 + (size_t)j * 1536 + 1024;
    const float* at = attr2_tab + a * 512;
    float d = 0.f;
    for (int i = 0; i < 512; ++i) d += w[i] * at[i];
    t2[gid] = d + b1[j];
  } else {
    int idx = (bid - 16) * 256 + threadIdx.x;   // 0..32767, 16 floats each
    const float* src = Wc + (size_t)idx * 16;
    f32x4 a0 = *(const f32x4*)src;
    f32x4 a1 = *(const f32x4*)(src + 4);
    f32x4 a2 = *(const f32x4*)(src + 8);
    f32x4 a3 = *(const f32x4*)(src + 12);
    unsigned int* dp = (unsigned int*)&wcbf[(size_t)idx * 16];
    dp[0] = pkbf(a0.x, a0.y); dp[1] = pkbf(a0.z, a0.w);
    dp[2] = pkbf(a1.x, a1.y); dp[3] = pkbf(a1.z, a1.w);
    dp[4] = pkbf(a2.x, a2.y); dp[5] = pkbf(a2.z, a2.w);
    dp[6] = pkbf(a3.x, a3.y); dp[7] = pkbf(a3.z, a3.w);
  }
}

// ---------------- main: conv+BN+tanh+attr-dot -> softmax -> feat ------------
// One WG (256 thr, 4 waves) per batch b. Wave w owns hw-tile group
// {t0..t0+ntile-1} (t0 = 3w; wave 3 gets 4 tiles incl. the zero-padded tile 12)
// and all 128 o's of the current o-chunk.
// v2: K-chunk 64 (64 rounds instead of 128); A-tile staged TRANSPOSED into
// Xt[hw][c] bf16 with an XOR swizzle on 8B units so A-fragments are single
// ds_read_b128 (was 8x ds_read_u16); Wc pre-converted to bf16 (pure b128
// copy staging, no per-round convert VALU).
__global__ __launch_bounds__(256, 2) void k_main(
    const float* __restrict__ x, const unsigned short* __restrict__ wcbf,
    const int* __restrict__ cidx, const float* __restrict__ attr1_tab,
    const float* __restrict__ bnA, const float* __restrict__ bnB,
    float* __restrict__ feat) {
  // Xt: [hw 0..207][64 c] bf16, row pad to 72 u16 (144B, 16B-aligned rows).
  // 8B-unit u within a row stores source c-quad (u ^ s(hw)), s = ((hw>>2)&7)<<1.
  __shared__ __align__(16) unsigned short Xt[208 * 72];   // 29.25 KB
  __shared__ __align__(16) unsigned short Wl[128 * 72];   // [o][c] pad 72, 18 KB
  __shared__ float attr_l[512], bnA_l[512], bnB_l[512];
  __shared__ float s_lds[HW2];
  __shared__ float red[8];

  int b = blockIdx.x, tid = threadIdx.x;
  int wid = tid >> 6, lane = tid & 63, quad = lane >> 4, l15 = lane & 15;

  int ca = cidx[b];
  for (int i = tid; i < 512; i += 256) {
    attr_l[i] = attr1_tab[ca * 512 + i];
    bnA_l[i] = bnA[i];
    bnB_l[i] = bnB[i];
  }
  // zero pad rows 196..207 once (tile 12 reads them as zeros); 432 u32
  {
    unsigned int* zp = (unsigned int*)&Xt[196 * 72];
    for (int i = tid; i < 432; i += 256) zp[i] = 0u;
  }

  const float* xb = x + (size_t)b * (CIN * HW2);
  int t0 = wid * 3;
  int ntile = (wid == 3) ? 4 : 3;

  float sv[4][4];
#pragma unroll
  for (int mt = 0; mt < 4; ++mt)
#pragma unroll
    for (int r = 0; r < 4; ++r) sv[mt][r] = 0.f;

  for (int och = 0; och < 4; ++och) {
    int o_base = och * 128;
    f32x4 acc[4][8];
#pragma unroll
    for (int mt = 0; mt < 4; ++mt)
#pragma unroll
      for (int q = 0; q < 8; ++q) {
        f32x4 z = {0.f, 0.f, 0.f, 0.f};
        acc[mt][q] = z;
      }
    for (int kt = 0; kt < 16; ++kt) {
      __syncthreads();
      int c0 = kt * 64;
      // ---- stage Xt: 784 tasks = 16 c-quads x 49 hw4; 4x4 reg transpose ----
      const float* xs = xb + (size_t)c0 * HW2;
#pragma unroll
      for (int it = 0; it < 4; ++it) {
        int id = it * 256 + tid;
        if (id < 784) {
          int cq = id / 49;            // 0..15 (4 c's each)
          int hw4 = id - cq * 49;      // 0..48 (4 hw's each)
          const float* p = xs + (size_t)cq * (4 * HW2) + hw4 * 4;
          f32x4 v0 = *(const f32x4*)p;
          f32x4 v1 = *(const f32x4*)(p + HW2);
          f32x4 v2 = *(const f32x4*)(p + 2 * HW2);
          f32x4 v3 = *(const f32x4*)(p + 3 * HW2);
          int s = (hw4 & 7) << 1;                 // == ((hw>>2)&7)<<1 for these rows
          int ub = (cq ^ s) << 2;                 // u16 offset of swizzled 8B unit
#pragma unroll
          for (int r = 0; r < 4; ++r) {
            unsigned long long wv =
                (unsigned long long)pkbf(v0[r], v1[r]) |
                ((unsigned long long)pkbf(v2[r], v3[r]) << 32);
            *(unsigned long long*)&Xt[(hw4 * 4 + r) * 72 + ub] = wv;
          }
        }
      }
      // ---- stage Wl: 1024 16B-chunks, pure bf16 copy ----
#pragma unroll
      for (int it = 0; it < 4; ++it) {
        int ch = it * 256 + tid;
        int row = ch >> 3, u = ch & 7;
        s16x8 v = *(const s16x8*)&wcbf[(size_t)(o_base + row) * CIN + c0 + u * 8];
        *(s16x8*)&Wl[row * 72 + u * 8] = v;
      }
      __syncthreads();
      // ---- fragments + MFMA: K=64 as two K=32 sub-steps ----
#pragma unroll
      for (int kk = 0; kk < 2; ++kk) {
        s16x8 af[4];
#pragma unroll
        for (int mt = 0; mt < 4; ++mt)
          if (mt < ntile) {
            int hw = (t0 + mt) * 16 + l15;
            int s = ((hw >> 2) & 7) << 1;
            int u = (kk << 3) + (quad << 1);
            af[mt] = *(const s16x8*)&Xt[hw * 72 + ((u ^ s) << 2)];
          }
#pragma unroll
        for (int h = 0; h < 2; ++h) {
          s16x8 bfr[4];
#pragma unroll
          for (int nt = 0; nt < 4; ++nt)
            bfr[nt] = *(const s16x8*)&Wl[(h * 64 + nt * 16 + l15) * 72 + kk * 32 + quad * 8];
#pragma unroll
          for (int mt = 0; mt < 4; ++mt)
            if (mt < ntile) {
#pragma unroll
              for (int nt = 0; nt < 4; ++nt)
                acc[mt][h * 4 + nt] = __builtin_amdgcn_mfma_f32_16x16x32_bf16(
                    af[mt], bfr[nt], acc[mt][h * 4 + nt], 0, 0, 0);
            }
        }
      }
    }
    // epilogue: BN + tanh + attr-dot, accumulate per-lane partials
    float at[8], sa[8], sb[8];
#pragma unroll
    for (int q = 0; q < 8; ++q) {
      int o = o_base + q * 16 + l15;
      at[q] = attr_l[o]; sa[q] = bnA_l[o]; sb[q] = bnB_l[o];
    }
#pragma unroll
    for (int mt = 0; mt < 4; ++mt)
      if (mt < ntile) {
#pragma unroll
        for (int r = 0; r < 4; ++r) {
          float v = 0.f;
#pragma unroll
          for (int q = 0; q < 8; ++q)
            v += at[q] * tanh_fast(acc[mt][q][r] * sa[q] + sb[q]);
          sv[mt][r] += v;
        }
      }
  }
  // reduce over l15 (o-cols) and write attention scores
#pragma unroll
  for (int mt = 0; mt < 4; ++mt)
    if (mt < ntile) {
#pragma unroll
      for (int r = 0; r < 4; ++r) {
        float v = sv[mt][r];
        v += __shfl_xor(v, 1);
        v += __shfl_xor(v, 2);
        v += __shfl_xor(v, 4);
        v += __shfl_xor(v, 8);
        int hw = (t0 + mt) * 16 + quad * 4 + r;
        if (l15 == 0 && hw < HW2) s_lds[hw] = v;
      }
    }
  __syncthreads();
  // softmax over 196 (scaled by 1/sqrt(512))
  {
    float v = (tid < HW2) ? s_lds[tid] * 0.04419417382415922f : -1e30f;
    float m = v;
    for (int off = 32; off > 0; off >>= 1) m = fmaxf(m, __shfl_xor(m, off));
    if (lane == 0) red[wid] = m;
    __syncthreads();
    float gm = fmaxf(fmaxf(red[0], red[1]), fmaxf(red[2], red[3]));
    float e = (tid < HW2) ? __expf(v - gm) : 0.f;
    float s = e;
    for (int off = 32; off > 0; off >>= 1) s += __shfl_xor(s, off);
    __syncthreads();
    if (lane == 0) red[wid] = s;
    __syncthreads();
    float gs = red[0] + red[1] + red[2] + red[3];
    if (tid < HW2) s_lds[tid] = e / gs;
  }
  __syncthreads();
  // feat[b][c] = sum_hw x[b][c][hw] * attmap[hw]  (native layout, fp32)
  for (int cc = tid; cc < 1024; cc += 256) {
    const float* xr = xb + (size_t)cc * HW2;
    float a = 0.f;
#pragma unroll
    for (int h4 = 0; h4 < 49; ++h4) {
      f32x4 v = *(const f32x4*)(xr + h4 * 4);
      a += s_lds[h4 * 4 + 0] * v.x + s_lds[h4 * 4 + 1] * v.y +
           s_lds[h4 * 4 + 2] * v.z + s_lds[h4 * 4 + 3] * v.w;
    }
    feat[(size_t)b * 1024 + cc] = a;
  }
}

// ---------------- MLP + gate + l2norm, 2 batches per WG ---------------------
__device__ __forceinline__ void dot8(const float* __restrict__ w,
                                     const float* __restrict__ fa, const float* __restrict__ fb,
                                     int i, float& a0, float& a1) {
  f32x4 wa = *(const f32x4*)(w + i);
  f32x4 wb = *(const f32x4*)(w + i + 4);
  a0 += wa.x * fa[i+0]; a1 += wa.x * fb[i+0];
  a0 += wa.y * fa[i+1]; a1 += wa.y * fb[i+1];
  a0 += wa.z * fa[i+2]; a1 += wa.z * fb[i+2];
  a0 += wa.w * fa[i+3]; a1 += wa.w * fb[i+3];
  a0 += wb.x * fa[i+4]; a1 += wb.x * fb[i+4];
  a0 += wb.y * fa[i+5]; a1 += wb.y * fb[i+5];
  a0 += wb.z * fa[i+6]; a1 += wb.z * fb[i+6];
  a0 += wb.w * fa[i+7]; a1 += wb.w * fb[i+7];
}

__global__ __launch_bounds__(512) void k_mlp(
    const float* __restrict__ feat, const int* __restrict__ cidx, const float* __restrict__ t2,
    const float* __restrict__ W1, const float* __restrict__ W2,
    const float* __restrict__ b2, const float* __restrict__ Wf,
    const float* __restrict__ bfb, float* __restrict__ out) {
  __shared__ float f0[1024], f1[1024];
  __shared__ float h0[512], h1[512];
  __shared__ float g0[1024], g1[1024];
  __shared__ float red[16];
  int tid = threadIdx.x;
  int b0 = blockIdx.x * 2, b1 = b0 + 1;
  int c0 = cidx[b0], c1 = cidx[b1];
  for (int i = tid; i < 1024; i += 512) {
    f0[i] = feat[(size_t)b0 * 1024 + i];
    f1[i] = feat[(size_t)b1 * 1024 + i];
  }
  __syncthreads();
  {  // h = relu(W1[:, :1024] @ feat + t2[c])
    int j = tid;
    const float* w = W1 + (size_t)j * 1536;
    float a0 = 0.f, a1 = 0.f;
    for (int i = 0; i < 1024; i += 8) dot8(w, f0, f1, i, a0, a1);
    h0[j] = fmaxf(a0 + t2[c0 * 512 + j], 0.f);
    h1[j] = fmaxf(a1 + t2[c1 * 512 + j], 0.f);
  }
  __syncthreads();
  for (int m = tid; m < 1024; m += 512) {  // gate
    const float* w = W2 + (size_t)m * 512;
    float a0 = 0.f, a1 = 0.f;
    for (int i = 0; i < 512; i += 8) dot8(w, h0, h1, i, a0, a1);
    float bb = b2[m];
    float s0 = 1.f / (1.f + __expf(-(a0 + bb)));
    float s1 = 1.f / (1.f + __expf(-(a1 + bb)));
    g0[m] = f0[m] * s0;
    g1[m] = f1[m] * s1;
  }
  __syncthreads();
  float o0[2], o1[2];
  float ss0 = 0.f, ss1 = 0.f;
#pragma unroll
  for (int t = 0; t < 2; ++t) {  // out = g @ Wf^T + bf
    int e = tid + t * 512;
    const float* w = Wf + (size_t)e * 1024;
    float a0 = 0.f, a1 = 0.f;
    for (int i = 0; i < 1024; i += 8) dot8(w, g0, g1, i, a0, a1);
    float bb = bfb[e];
    a0 += bb; a1 += bb;
    o0[t] = a0; o1[t] = a1;
    ss0 += a0 * a0; ss1 += a1 * a1;
  }
  for (int off = 32; off > 0; off >>= 1) {
    ss0 += __shfl_xor(ss0, off);
    ss1 += __shfl_xor(ss1, off);
  }
  int wid = tid >> 6, lane = tid & 63;
  if (lane == 0) { red[wid] = ss0; red[wid + 8] = ss1; }
  __syncthreads();
  float t0 = 0.f, t1 = 0.f;
#pragma unroll
  for (int w = 0; w < 8; ++w) { t0 += red[w]; t1 += red[w + 8]; }
  float n0 = rsqrtf(t0), n1 = rsqrtf(t1);
#pragma unroll
  for (int t = 0; t < 2; ++t) {
    int e = tid + t * 512;
    out[(size_t)b0 * 1024 + e] = o0[t] * n0;
    out[(size_t)b1 * 1024 + e] = o1[t] * n1;
  }
}

extern "C" void kernel_launch(void* const* d_in, const int* in_sizes, int n_in,
                              void* d_out, int out_size, void* d_ws, size_t ws_size,
                              hipStream_t stream) {
  const float* x        = (const float*)d_in[0];
  const int*   c        = (const int*)d_in[1];
  const float* attr_emb = (const float*)d_in[2];
  const float* Wt1      = (const float*)d_in[3];
  const float* bt1      = (const float*)d_in[4];
  const float* Wc       = (const float*)d_in[5];
  const float* bc       = (const float*)d_in[6];
  const float* gamma    = (const float*)d_in[7];
  const float* beta     = (const float*)d_in[8];
  const float* mean     = (const float*)d_in[9];
  const float* var      = (const float*)d_in[10];
  const float* Wt2      = (const float*)d_in[11];
  const float* bt2      = (const float*)d_in[12];
  const float* W1       = (const float*)d_in[13];
  const float* b1       = (const float*)d_in[14];
  const float* W2       = (const float*)d_in[15];
  const float* b2       = (const float*)d_in[16];
  const float* Wf       = (const float*)d_in[17];
  const float* bfb      = (const float*)d_in[18];

  // workspace: ~3.2 MB
  char* ws = (char*)d_ws;
  float* feat      = (float*)ws;                         // 512*1024*4 = 2 MB
  float* attr1_tab = (float*)(ws + 2097152);             // 16 KB
  float* attr2_tab = attr1_tab + 4096;
  float* t2        = attr2_tab + 4096;
  float* bnA       = t2 + 4096;
  float* bnB       = bnA + 512;
  unsigned short* wcbf = (unsigned short*)(ws + 2150400); // 1 MB, 512x1024 bf16

  hipLaunchKernelGGL(k_pre1, dim3(18), dim3(256), 0, stream,
                     attr_emb, Wt1, bt1, Wt2, bt2, bc, gamma, beta, mean, var,
                     attr1_tab, attr2_tab, bnA, bnB);
  hipLaunchKernelGGL(k_pre2, dim3(144), dim3(256), 0, stream,
                     W1, b1, attr2_tab, t2, Wc, wcbf);
  hipLaunchKernelGGL(k_main, dim3(512), dim3(256), 0, stream,
                     x, wcbf, c, attr1_tab, bnA, bnB, feat);
  hipLaunchKernelGGL(k_mlp, dim3(256), dim3(512), 0, stream,
                     feat, c, t2, W1, W2, b2, Wf, bfb, (float*)d_out);
}